// Round 1
// baseline (225.769 us; speedup 1.0000x reference)
//
#include <hip/hip_runtime.h>

// PositionalEncoder: out[k] = sum_j ((1 - j/J) - (k/d)*(1 - 2j/J)) * E[j,k]
// j = 1..J (row+1), k = 1..d (col+1). E is row-major [J, D] float32.
// Memory-bound column reduction: 128 MiB read once -> ~21 us HBM floor.

constexpr int D_COLS = 2048;
constexpr int J_ROWS = 16384;
constexpr int T1 = 512;          // threads per stage-1 block (covers D_COLS via float4)
constexpr int B1_MAX = 512;      // stage-1 blocks (4 MiB of ws partials)

// Stage 1: block b reduces rows {b, b+nb, b+2nb, ...} into ws[b*D + col].
// Each thread owns 4 consecutive columns -> float4 loads, fully coalesced;
// one block's 512 threads span the entire 2048-column row.
__global__ __launch_bounds__(T1) void pe_stage1(const float* __restrict__ E,
                                                float* __restrict__ ws,
                                                int nb) {
    const int tid  = threadIdx.x;
    const int col0 = tid * 4;
    const float invJ = 1.0f / (float)J_ROWS;
    const float invD = 1.0f / (float)D_COLS;
    // c_k = k/d for this thread's 4 columns (k = col+1) — loop-invariant
    const float c0 = (float)(col0 + 1) * invD;
    const float c1 = (float)(col0 + 2) * invD;
    const float c2 = (float)(col0 + 3) * invD;
    const float c3 = (float)(col0 + 4) * invD;

    float4 acc = make_float4(0.f, 0.f, 0.f, 0.f);
    for (int row = blockIdx.x; row < J_ROWS; row += nb) {
        const float jf = (float)(row + 1);
        const float a = fmaf(-jf,        invJ, 1.0f);   // 1 - j/J
        const float b = fmaf(-2.0f * jf, invJ, 1.0f);   // 1 - 2j/J
        const float4 e = *reinterpret_cast<const float4*>(E + (size_t)row * D_COLS + col0);
        acc.x = fmaf(fmaf(-c0, b, a), e.x, acc.x);
        acc.y = fmaf(fmaf(-c1, b, a), e.y, acc.y);
        acc.z = fmaf(fmaf(-c2, b, a), e.z, acc.z);
        acc.w = fmaf(fmaf(-c3, b, a), e.w, acc.w);
    }
    *reinterpret_cast<float4*>(ws + (size_t)blockIdx.x * D_COLS + col0) = acc;
}

// Stage 2: out[k] = sum_b ws[b*D + k]. One thread per column; consecutive
// threads hit consecutive addresses (coalesced). 4 accumulators for ILP.
__global__ __launch_bounds__(256) void pe_stage2(const float* __restrict__ ws,
                                                 float* __restrict__ out,
                                                 int nb) {
    const int k = blockIdx.x * 256 + threadIdx.x;
    if (k >= D_COLS) return;
    float s0 = 0.f, s1 = 0.f, s2 = 0.f, s3 = 0.f;
    int b = 0;
    for (; b + 3 < nb; b += 4) {
        s0 += ws[(size_t)(b + 0) * D_COLS + k];
        s1 += ws[(size_t)(b + 1) * D_COLS + k];
        s2 += ws[(size_t)(b + 2) * D_COLS + k];
        s3 += ws[(size_t)(b + 3) * D_COLS + k];
    }
    for (; b < nb; ++b) s0 += ws[(size_t)b * D_COLS + k];
    out[k] = (s0 + s1) + (s2 + s3);
}

extern "C" void kernel_launch(void* const* d_in, const int* in_sizes, int n_in,
                              void* d_out, int out_size, void* d_ws, size_t ws_size,
                              hipStream_t stream) {
    const float* E = (const float*)d_in[0];
    float* out = (float*)d_out;
    float* ws = (float*)d_ws;

    // Shrink stage-1 grid if workspace is tight (needs nb * D * 4 bytes).
    int nb = B1_MAX;
    const size_t per_block = (size_t)D_COLS * sizeof(float);
    if (ws_size < (size_t)nb * per_block) {
        nb = (int)(ws_size / per_block);
        if (nb < 1) nb = 1;  // degenerate; assume harness gives >= 8 KiB
    }

    pe_stage1<<<nb, T1, 0, stream>>>(E, ws, nb);
    pe_stage2<<<(D_COLS + 255) / 256, 256, 0, stream>>>(ws, out, nb);
}